// Round 3
// baseline (534.637 us; speedup 1.0000x reference)
//
#include <hip/hip_runtime.h>
#include <hip/hip_bf16.h>

typedef __hip_bfloat16 bf16;

#define BB 4
#define SS 2048
#define DD 1024
#define HH 16
#define FF 4096
#define HD 64
#define LN_EPS 1e-5f
#define QSCALE 0.1803368801111204f  // 0.125 * log2(e): softmax in exp2 domain

typedef __attribute__((ext_vector_type(8))) __bf16 bf16x8;
typedef __attribute__((ext_vector_type(8))) unsigned short u16x8;
typedef __attribute__((ext_vector_type(4))) float f32x4;

__device__ __forceinline__ float cvt(float v) { return v; }
__device__ __forceinline__ float cvt(bf16 v) { return __bfloat162float(v); }
__device__ __forceinline__ void stf(float* p, float v) { *p = v; }
__device__ __forceinline__ void stf(bf16* p, float v) { *p = __float2bfloat16(v); }

// fp32 -> bf16 round-to-nearest-even
__device__ __forceinline__ unsigned short f2bf_rne(float x) {
    unsigned int u = __float_as_uint(x);
    unsigned int r = (u + 0x7fffu + ((u >> 16) & 1u)) >> 16;
    return (unsigned short)r;
}

// async global->LDS, 16B/lane; LDS dest lane-contiguous (m104/m108).
// Global-side address carries the XOR swizzle (measured 0 conflicts).
__device__ __forceinline__ void async_cp16(const void* g, void* l) {
    __builtin_amdgcn_global_load_lds(
        (const __attribute__((address_space(1))) unsigned int*)g,
        (__attribute__((address_space(3))) unsigned int*)l, 16, 0, 0);
}

// Counted vmcnt wait: lets N loads stay in flight across the barrier (T4).
template <int N>
__device__ __forceinline__ void s_wait_vmcnt() {
    asm volatile("s_waitcnt vmcnt(%0)" ::"n"(N) : "memory");
    __builtin_amdgcn_sched_barrier(0);
}

// Raw workgroup barrier WITHOUT the __syncthreads vmcnt(0) drain.
__device__ __forceinline__ void sync_raw() {
    asm volatile("" ::: "memory");
    __builtin_amdgcn_s_barrier();
    asm volatile("" ::: "memory");
    __builtin_amdgcn_sched_barrier(0);
}

__device__ __forceinline__ void wait_lds() {
    asm volatile("s_waitcnt lgkmcnt(0)" ::: "memory");
    __builtin_amdgcn_sched_barrier(0);  // rule #18: pin MFMA below the wait
}

__device__ __forceinline__ u16x8 ld_f32_chunk(const float* p) {
    const float4* q = (const float4*)p;
    const float4 a = q[0], b = q[1];
    u16x8 r;
    r[0] = f2bf_rne(a.x); r[1] = f2bf_rne(a.y); r[2] = f2bf_rne(a.z); r[3] = f2bf_rne(a.w);
    r[4] = f2bf_rne(b.x); r[5] = f2bf_rne(b.y); r[6] = f2bf_rne(b.z); r[7] = f2bf_rne(b.w);
    return r;
}

// ---------------------------------------------------------------------------
// R13: 8-wave pipelined MFMA GEMM, m201 geometry. C = A(MxK) @ B(KxN),
// A bf16, B TRANSPOSED (NxK bf16).  BM=256, BN in {256,128}, BK=64.
// Wave grid WM x WN; per-wave tile (BM/WM) x (BN/WN).
// LDS-BW roofline note: per-K-tile LDS read volume = WN*|A| + WM*|B|;
// FLOP/LDS-byte: <256,2,4> = 42.7 (above knee ~32), <128,4,2> = 32 (knee).
// NO redundant frag reads: bq once/K-tile, af once per mh-half.
// Pipeline: dbuf, 1-tile lead. Iter t: issue A-stage(t+1)->buf^1, then
// vmcnt(ALD) retires exactly tile t (t+1's A stays in flight a full iter);
// B-stage(t+1) split across the two mh-phases. Raw barriers (no vmcnt(0)
// drain in main loop); setprio(1) around MFMA clusters (T5).
// Race-freedom: buf^1's last readers ran in iter t-1, separated from iter
// t's stage-writes by iter t-1's end barrier. vmcnt+barrier at iter start
// collectively publishes all of tile t before any wave reads it.
// EPI 2: relu(gemm+bias)  EPI 5: fused QKV (Q*oscale | K | V-transposed)
// EPI 6: gemm+bias+res    EPI 7: gemm+res
// ---------------------------------------------------------------------------
template <int BN, int WM, int WN, int EPI>
__launch_bounds__(512, 2)
__global__ void gemm8w(const bf16* __restrict__ Abf, const bf16* __restrict__ Bt,
                       bf16* __restrict__ C, const float* __restrict__ bias,
                       const bf16* __restrict__ resb,
                       bf16* __restrict__ C2, bf16* __restrict__ C3,
                       int M, int N, int K, float oscale) {
    static_assert(WM * WN == 8, "8 waves");
    constexpr int BM = 256;
    constexpr int PWM = BM / WM;   // rows per wave
    constexpr int PWN = BN / WN;   // cols per wave
    constexpr int MI = PWM / 16;   // m-frags per wave
    constexpr int NJ = PWN / 16;   // n-frags per wave
    constexpr int MH = MI / 2;     // m-frags per phase
    constexpr int ALD = BM / 64;   // A-stage loads/thread/tile (4)
    constexpr int BLD = BN / 64;   // B-stage loads/thread/tile (4 or 2)

    __shared__ unsigned short As[2][BM * 64];
    __shared__ unsigned short Bs[2][BN * 64];

    const int tid = threadIdx.x;
    const int lane = tid & 63;
    const int w = tid >> 6;
    const int wm = w / WN, wn = w % WN;
    const int ln = lane & 15;
    const int qd = lane >> 4;

    // ---- XCD-chunked bijective swizzle (T1). HW: XCD = orig_id % 8. ----
    const int nwg = gridDim.x * gridDim.y;
    const int id = blockIdx.y * gridDim.x + blockIdx.x;
    const int cpx = nwg >> 3;                      // nwg % 8 == 0 guaranteed
    const int swz = (id & 7) * cpx + (id >> 3);
    const int bx = swz % gridDim.x, by = swz / gridDim.x;
    const int m0 = by * BM, n0 = bx * BN;

    const unsigned short* Ag = (const unsigned short*)Abf;
    const unsigned short* Bg = (const unsigned short*)Bt;

    const unsigned short* agp[ALD];
    const unsigned short* bgp[BLD];
    int aof[ALD], bof[BLD];
#pragma unroll
    for (int i = 0; i < ALD; ++i) {
        const int ff = tid + i * 512, fr = ff >> 3, fg = (ff & 7) ^ (fr & 7);
        agp[i] = Ag + (size_t)(m0 + fr) * K + fg * 8;
        aof[i] = ff * 8;
    }
#pragma unroll
    for (int i = 0; i < BLD; ++i) {
        const int ff = tid + i * 512, fr = ff >> 3, fg = (ff & 7) ^ (fr & 7);
        bgp[i] = Bg + (size_t)(n0 + fr) * K + fg * 8;
        bof[i] = ff * 8;
    }

    auto stageA = [&](int kt, int buf) {
#pragma unroll
        for (int i = 0; i < ALD; ++i) async_cp16(agp[i] + kt * 64, &As[buf][aof[i]]);
    };
    auto stageBh = [&](int kt, int buf, int h) {
#pragma unroll
        for (int i = 0; i < BLD / 2; ++i) {
            const int k = h * (BLD / 2) + i;
            async_cp16(bgp[k] + kt * 64, &Bs[buf][bof[k]]);
        }
    };

    f32x4 acc[MI][NJ];
#pragma unroll
    for (int i = 0; i < MI; ++i)
#pragma unroll
        for (int j = 0; j < NJ; ++j) acc[i][j] = (f32x4){0.f, 0.f, 0.f, 0.f};

    const int nt = K >> 6;
    stageA(0, 0);
    stageBh(0, 0, 0);
    stageBh(0, 0, 1);

    for (int t = 0; t < nt; ++t) {
        const int cur = t & 1, nxt = cur ^ 1;
        // A-stage of t+1 first, then counted wait: retires tile t's loads
        // exactly, keeps t+1's A in flight across this whole iteration.
        if (t + 1 < nt) {
            stageA(t + 1, nxt);
            s_wait_vmcnt<ALD>();
        } else {
            s_wait_vmcnt<0>();
        }
        sync_raw();  // publish tile t block-wide

        // ---- phase 0 (mh=0): B frags (whole tile) + A half 0 ----
        if (t + 1 < nt) stageBh(t + 1, nxt, 0);
        bf16x8 bq[NJ][2];
#pragma unroll
        for (int j = 0; j < NJ; ++j) {
            const int col = wn * PWN + j * 16 + ln;
#pragma unroll
            for (int ks = 0; ks < 2; ++ks) {
                const int g = ks * 4 + qd;
                bq[j][ks] = *(const bf16x8*)&Bs[cur][col * 64 + (g ^ (col & 7)) * 8];
            }
        }
        bf16x8 af0[MH][2];
#pragma unroll
        for (int i = 0; i < MH; ++i) {
            const int row = wm * PWM + i * 16 + ln;
#pragma unroll
            for (int ks = 0; ks < 2; ++ks) {
                const int g = ks * 4 + qd;
                af0[i][ks] = *(const bf16x8*)&As[cur][row * 64 + (g ^ (row & 7)) * 8];
            }
        }
        wait_lds();
        __builtin_amdgcn_s_setprio(1);
#pragma unroll
        for (int ks = 0; ks < 2; ++ks)
#pragma unroll
            for (int i = 0; i < MH; ++i)
#pragma unroll
                for (int j = 0; j < NJ; ++j)
                    acc[i][j] = __builtin_amdgcn_mfma_f32_16x16x32_bf16(
                        af0[i][ks], bq[j][ks], acc[i][j], 0, 0, 0);
        __builtin_amdgcn_s_setprio(0);
        __builtin_amdgcn_sched_barrier(0);
        sync_raw();

        // ---- phase 1 (mh=1): A half 1 (B frags already in regs) ----
        if (t + 1 < nt) stageBh(t + 1, nxt, 1);
        bf16x8 af1[MH][2];
#pragma unroll
        for (int i = 0; i < MH; ++i) {
            const int row = wm * PWM + (MH + i) * 16 + ln;
#pragma unroll
            for (int ks = 0; ks < 2; ++ks) {
                const int g = ks * 4 + qd;
                af1[i][ks] = *(const bf16x8*)&As[cur][row * 64 + (g ^ (row & 7)) * 8];
            }
        }
        wait_lds();
        __builtin_amdgcn_s_setprio(1);
#pragma unroll
        for (int ks = 0; ks < 2; ++ks)
#pragma unroll
            for (int i = 0; i < MH; ++i)
#pragma unroll
                for (int j = 0; j < NJ; ++j)
                    acc[MH + i][j] = __builtin_amdgcn_mfma_f32_16x16x32_bf16(
                        af1[i][ks], bq[j][ks], acc[MH + i][j], 0, 0, 0);
        __builtin_amdgcn_s_setprio(0);
        __builtin_amdgcn_sched_barrier(0);
        sync_raw();  // end barrier: buf cur dead, licenses next iter's stage
    }

    // Epilogue. C/D layout: col = lane&15, row = (lane>>4)*4 + reg.
#pragma unroll
    for (int i = 0; i < MI; ++i) {
        const int mrow0 = m0 + wm * PWM + i * 16 + qd * 4;
#pragma unroll
        for (int j = 0; j < NJ; ++j) {
            const int n = n0 + wn * PWN + j * 16 + ln;
            if (EPI == 5) {
                const int reg = n >> 10;  // tile-uniform: 0=Q, 1=K, 2=V
                const int nn = n & 1023;
                if (reg == 0) {
#pragma unroll
                    for (int r = 0; r < 4; ++r)
                        stf((bf16*)C + (size_t)(mrow0 + r) * 1024 + nn, acc[i][j][r] * oscale);
                } else if (reg == 1) {
#pragma unroll
                    for (int r = 0; r < 4; ++r)
                        stf(C2 + (size_t)(mrow0 + r) * 1024 + nn, acc[i][j][r]);
                } else {
                    const int bb = mrow0 >> 11, s = mrow0 & 2047;
                    ushort4 pk;
                    pk.x = f2bf_rne(acc[i][j][0]);
                    pk.y = f2bf_rne(acc[i][j][1]);
                    pk.z = f2bf_rne(acc[i][j][2]);
                    pk.w = f2bf_rne(acc[i][j][3]);
                    *(ushort4*)((unsigned short*)C3 + ((size_t)bb * 1024 + nn) * SS + s) = pk;
                }
            } else {
#pragma unroll
                for (int r = 0; r < 4; ++r) {
                    const size_t idx = (size_t)(mrow0 + r) * N + n;
                    float v = acc[i][j][r];
                    if (EPI == 2) { v += bias[n]; v = fmaxf(v, 0.0f); }
                    if (EPI == 6) v += bias[n] + cvt(resb[idx]);
                    if (EPI == 7) v += cvt(resb[idx]);
                    stf(&C[idx], v);
                }
            }
        }
    }
}

// ---------------------------------------------------------------------------
// R1-proven 128x128 MFMA GEMM (4 waves, 2 blocks/CU) — kept for Wo (small N).
// ---------------------------------------------------------------------------
template <typename TA, typename TC, int EPI>
__launch_bounds__(256)
__global__ void mfma_gemm(const TA* __restrict__ A, const bf16* __restrict__ Bt,
                          TC* __restrict__ C, const float* __restrict__ bias,
                          const bf16* __restrict__ resb,
                          bf16* __restrict__ C2, bf16* __restrict__ C3,
                          int M, int N, int K, float oscale) {
    constexpr bool AF = (sizeof(TA) == 4);
    __shared__ unsigned short As[128 * 64];
    __shared__ unsigned short Bs[128 * 64];

    const int tid = threadIdx.x;
    const int lane = tid & 63;
    const int w = tid >> 6;
    const int wm = w >> 1, wn = w & 1;

    const int nwg = gridDim.x * gridDim.y;
    const int id = blockIdx.y * gridDim.x + blockIdx.x;
    const int cpx = nwg >> 3;
    const int swz = (id & 7) * cpx + (id >> 3);
    const int bx = swz % gridDim.x, by = swz / gridDim.x;
    const int m0 = by * 128, n0 = bx * 128;

    int ff[4], fr[4], fg[4];
#pragma unroll
    for (int i = 0; i < 4; ++i) {
        ff[i] = tid + i * 256;
        fr[i] = ff[i] >> 3;
        fg[i] = (ff[i] & 7) ^ (fr[i] & 7);
    }

    f32x4 acc[4][4];
#pragma unroll
    for (int i = 0; i < 4; ++i)
#pragma unroll
        for (int j = 0; j < 4; ++j) acc[i][j] = (f32x4){0.f, 0.f, 0.f, 0.f};

    u16x8 sa[4];
    if (AF) {
#pragma unroll
        for (int i = 0; i < 4; ++i)
            sa[i] = ld_f32_chunk((const float*)A + (size_t)(m0 + fr[i]) * K + fg[i] * 8);
    }

    for (int k0 = 0; k0 < K; k0 += 64) {
        if (k0 > 0) __syncthreads();
        if (AF) {
#pragma unroll
            for (int i = 0; i < 4; ++i)
                *(u16x8*)&As[ff[i] * 8] = sa[i];
        } else {
#pragma unroll
            for (int i = 0; i < 4; ++i)
                async_cp16((const unsigned short*)A + (size_t)(m0 + fr[i]) * K + k0 + fg[i] * 8,
                           &As[ff[i] * 8]);
        }
#pragma unroll
        for (int i = 0; i < 4; ++i)
            async_cp16((const unsigned short*)Bt + (size_t)(n0 + fr[i]) * K + k0 + fg[i] * 8,
                       &Bs[ff[i] * 8]);
        __syncthreads();

        if (AF && k0 + 64 < K) {
            const int kn = k0 + 64;
#pragma unroll
            for (int i = 0; i < 4; ++i)
                sa[i] = ld_f32_chunk((const float*)A + (size_t)(m0 + fr[i]) * K + kn + fg[i] * 8);
        }

#pragma unroll
        for (int ks = 0; ks < 2; ++ks) {
            bf16x8 af[4], bfr[4];
#pragma unroll
            for (int i = 0; i < 4; ++i) {
                const int row = wm * 64 + i * 16 + (lane & 15);
                const int col = wn * 64 + i * 16 + (lane & 15);
                const int g = ks * 4 + (lane >> 4);
                af[i]  = *(const bf16x8*)&As[row * 64 + (g ^ (row & 7)) * 8];
                bfr[i] = *(const bf16x8*)&Bs[col * 64 + (g ^ (col & 7)) * 8];
            }
#pragma unroll
            for (int i = 0; i < 4; ++i)
#pragma unroll
                for (int j = 0; j < 4; ++j)
                    acc[i][j] = __builtin_amdgcn_mfma_f32_16x16x32_bf16(
                        af[i], bfr[j], acc[i][j], 0, 0, 0);
        }
    }

#pragma unroll
    for (int i = 0; i < 4; ++i) {
        const int mrow0 = m0 + wm * 64 + i * 16 + (lane >> 4) * 4;
#pragma unroll
        for (int j = 0; j < 4; ++j) {
            const int n = n0 + wn * 64 + j * 16 + (lane & 15);
#pragma unroll
            for (int r = 0; r < 4; ++r) {
                const size_t idx = (size_t)(mrow0 + r) * N + n;
                float v = acc[i][j][r];
                if (EPI == 0) v *= oscale;
                if (EPI == 2) { v += bias[n]; v = fmaxf(v, 0.0f); }
                if (EPI == 6) v += bias[n] + cvt(resb[idx]);
                if (EPI == 7) v += cvt(resb[idx]);
                stf(&C[idx], v);
            }
        }
    }
}

// ---------------------------------------------------------------------------
// Fused prep: x->bf16 convert + ALL weight transposes (one launch).
// ---------------------------------------------------------------------------
__launch_bounds__(256)
__global__ void prep_kernel(const float* __restrict__ x,
                            const float* __restrict__ Wq, const float* __restrict__ Wk,
                            const float* __restrict__ Wv, const float* __restrict__ Wo,
                            const float* __restrict__ w_in, const float* __restrict__ w_out,
                            bf16* __restrict__ xb, bf16* __restrict__ WqkvT,
                            bf16* __restrict__ WoT, bf16* __restrict__ w_inT,
                            bf16* __restrict__ w_outT) {
    const int id = blockIdx.x;
    if (id < 8192) {
        const int i = id * 256 + threadIdx.x;
        const float4 v = ((const float4*)x)[i];
        ushort4 p;
        p.x = f2bf_rne(v.x); p.y = f2bf_rne(v.y); p.z = f2bf_rne(v.z); p.w = f2bf_rne(v.w);
        ((ushort4*)xb)[i] = p;
        return;
    }
    __shared__ float t[32][33];
    const int rem = id - 8192;
    const float* in;
    bf16* out;
    int R, C, bx, by;
    size_t in_o = 0, out_o = 0;
    if (rem < 3072) {
        const int z = rem >> 6, r2 = rem & 63;
        const int wi = z >> 4, head = z & 15;
        in = (wi == 0) ? Wq : (wi == 1) ? Wk : Wv;
        in_o = (size_t)head * DD * HD;
        out = WqkvT;
        out_o = (size_t)wi * DD * DD + (size_t)head * HD * DD;
        R = DD; C = HD;
        bx = (r2 & 1) * 32; by = (r2 >> 1) * 32;
    } else if (rem < 3072 + 1024) {
        const int r2 = rem - 3072;
        in = Wo; out = WoT; R = DD; C = DD;
        bx = (r2 & 31) * 32; by = (r2 >> 5) * 32;
    } else if (rem < 3072 + 1024 + 4096) {
        const int r2 = rem - 3072 - 1024;
        in = w_in; out = w_inT; R = DD; C = FF;
        bx = (r2 & 127) * 32; by = (r2 >> 7) * 32;
    } else {
        const int r2 = rem - 3072 - 1024 - 4096;
        in = w_out; out = w_outT; R = FF; C = DD;
        bx = (r2 & 31) * 32; by = (r2 >> 5) * 32;
    }
    const int tx = threadIdx.x & 31, ty = threadIdx.x >> 5;
#pragma unroll
    for (int i = 0; i < 32; i += 8)
        t[ty + i][tx] = in[in_o + (size_t)(by + ty + i) * C + bx + tx];
    __syncthreads();
#pragma unroll
    for (int i = 0; i < 32; i += 8)
        out[out_o + (size_t)(bx + ty + i) * R + by + tx] = __float2bfloat16(t[tx][ty + i]);
}

// ---------------------------------------------------------------------------
// MFMA causal flash attention (proven config — 64-key tiles).
// ---------------------------------------------------------------------------
__launch_bounds__(256, 4)
__global__ void attn_mfma(const bf16* __restrict__ Q, const bf16* __restrict__ K,
                          const bf16* __restrict__ VT, bf16* __restrict__ O) {
    __shared__ unsigned short Ks[64 * 64];
    __shared__ unsigned short Vs[64 * 64];
    __shared__ unsigned short Ps[64 * 72];

    const int tid = threadIdx.x;
    const int lane = tid & 63;
    const int w = tid >> 6;
    const int ln = lane & 15;
    const int qd = lane >> 4;
    const int bh = blockIdx.x;
    const int b = bh >> 4;
    const int h = bh & 15;
    const int qi = 31 - blockIdx.y;  // heavy blocks dispatch first
    const int q0 = qi * 64;

    bf16x8 aq[2];
    {
        const unsigned short* qp =
            (const unsigned short*)Q + ((size_t)b * SS + q0 + w * 16 + ln) * DD + h * HD;
        aq[0] = *(const bf16x8*)(qp + qd * 8);
        aq[1] = *(const bf16x8*)(qp + 32 + qd * 8);
    }

    int sf[2], sr[2], sg[2];
#pragma unroll
    for (int i = 0; i < 2; ++i) {
        sf[i] = tid + i * 256;
        sr[i] = sf[i] >> 3;
        sg[i] = (sf[i] & 7) ^ (sr[i] & 7);
    }
    const unsigned short* kbase = (const unsigned short*)K + (size_t)b * SS * DD + h * HD;
    const unsigned short* vbase = (const unsigned short*)VT + (size_t)(b * DD + h * HD) * SS;

    f32x4 oacc[4];
#pragma unroll
    for (int e = 0; e < 4; ++e) oacc[e] = (f32x4){0.f, 0.f, 0.f, 0.f};
    float l_r[4] = {0.f, 0.f, 0.f, 0.f};

    for (int kt = 0; kt <= qi; ++kt) {
        const int t0 = kt * 64;
        __syncthreads();
#pragma unroll
        for (int i = 0; i < 2; ++i) {
            async_cp16(kbase + (size_t)(t0 + sr[i]) * DD + sg[i] * 8, &Ks[sf[i] * 8]);
            async_cp16(vbase + (size_t)sr[i] * SS + t0 + sg[i] * 8, &Vs[sf[i] * 8]);
        }
        __syncthreads();

        f32x4 sfr[4];
#pragma unroll
        for (int ct = 0; ct < 4; ++ct) {
            const int row = ct * 16 + ln;
            const bf16x8 b0 = *(const bf16x8*)&Ks[row * 64 + ((qd) ^ (row & 7)) * 8];
            const bf16x8 b1 = *(const bf16x8*)&Ks[row * 64 + ((4 + qd) ^ (row & 7)) * 8];
            f32x4 t = __builtin_amdgcn_mfma_f32_16x16x32_bf16(
                aq[0], b0, (f32x4){0.f, 0.f, 0.f, 0.f}, 0, 0, 0);
            sfr[ct] = __builtin_amdgcn_mfma_f32_16x16x32_bf16(aq[1], b1, t, 0, 0, 0);
        }

        if (kt == qi) {
#pragma unroll
            for (int ct = 0; ct < 4; ++ct) {
                const int tg = t0 + ct * 16 + ln;
#pragma unroll
                for (int r = 0; r < 4; ++r) {
                    const int qg = q0 + w * 16 + qd * 4 + r;
                    if (tg > qg) sfr[ct][r] = -1e30f;
                }
            }
        }

#pragma unroll
        for (int ct = 0; ct < 4; ++ct)
#pragma unroll
            for (int r = 0; r < 4; ++r)
                sfr[ct][r] = __builtin_amdgcn_exp2f(sfr[ct][r]);
#pragma unroll
        for (int r = 0; r < 4; ++r)
            l_r[r] += (sfr[0][r] + sfr[1][r]) + (sfr[2][r] + sfr[3][r]);

#pragma unroll
        for (int ct = 0; ct < 4; ++ct)
#pragma unroll
            for (int r = 0; r < 4; ++r)
                Ps[(w * 16 + qd * 4 + r) * 72 + ct * 16 + ln] = f2bf_rne(sfr[ct][r]);
        const bf16x8 ap0 = *(const bf16x8*)&Ps[(w * 16 + ln) * 72 + qd * 8];
        const bf16x8 ap1 = *(const bf16x8*)&Ps[(w * 16 + ln) * 72 + 32 + qd * 8];

#pragma unroll
        for (int et = 0; et < 4; ++et) {
            const int row = et * 16 + ln;
            const bf16x8 v0 = *(const bf16x8*)&Vs[row * 64 + ((qd) ^ (row & 7)) * 8];
            const bf16x8 v1 = *(const bf16x8*)&Vs[row * 64 + ((4 + qd) ^ (row & 7)) * 8];
            oacc[et] = __builtin_amdgcn_mfma_f32_16x16x32_bf16(ap0, v0, oacc[et], 0, 0, 0);
            oacc[et] = __builtin_amdgcn_mfma_f32_16x16x32_bf16(ap1, v1, oacc[et], 0, 0, 0);
        }
    }

#pragma unroll
    for (int st = 1; st <= 8; st <<= 1)
#pragma unroll
        for (int r = 0; r < 4; ++r)
            l_r[r] += __shfl_xor(l_r[r], st);
    float linv[4];
#pragma unroll
    for (int r = 0; r < 4; ++r) linv[r] = 1.0f / l_r[r];
    unsigned short* ob = (unsigned short*)O + (size_t)bh * SS * HD;
#pragma unroll
    for (int et = 0; et < 4; ++et)
#pragma unroll
        for (int r = 0; r < 4; ++r) {
            const int qg = q0 + w * 16 + qd * 4 + r;
            ob[(size_t)qg * HD + et * 16 + ln] = f2bf_rne(oacc[et][r] * linv[r]);
        }
}

// ---------------------------------------------------------------------------
// LayerNorm over D=1024.
// ---------------------------------------------------------------------------
template <typename TIN, typename TOUT>
__launch_bounds__(256)
__global__ void ln_kernel(const TIN* __restrict__ X, TOUT* __restrict__ Y,
                          const float* __restrict__ g, const float* __restrict__ be) {
    const int row = blockIdx.x;
    const int tid = threadIdx.x;
    const int lane = tid & 63, w = tid >> 6;
    __shared__ float red[8];
    __shared__ float mv[2];

    float4 v;
    if (sizeof(TIN) == 4) {
        v = ((const float4*)((const float*)X + (size_t)row * DD))[tid];
    } else {
        const ushort4 u = ((const ushort4*)((const unsigned short*)X + (size_t)row * DD))[tid];
        v.x = __uint_as_float((unsigned)u.x << 16);
        v.y = __uint_as_float((unsigned)u.y << 16);
        v.z = __uint_as_float((unsigned)u.z << 16);
        v.w = __uint_as_float((unsigned)u.w << 16);
    }
    float s = (v.x + v.y) + (v.z + v.w);
    float q = (v.x * v.x + v.y * v.y) + (v.z * v.z + v.w * v.w);
#pragma unroll
    for (int st = 1; st < 64; st <<= 1) {
        s += __shfl_xor(s, st);
        q += __shfl_xor(q, st);
    }
    if (lane == 0) { red[w] = s; red[4 + w] = q; }
    __syncthreads();
    if (tid == 0) {
        const float ts = (red[0] + red[1]) + (red[2] + red[3]);
        const float tq = (red[4] + red[5]) + (red[6] + red[7]);
        const float mu = ts * (1.0f / DD);
        mv[0] = mu;
        mv[1] = rsqrtf(tq * (1.0f / DD) - mu * mu + LN_EPS);
    }
    __syncthreads();
    const float mu = mv[0], rs = mv[1];
    const float4 gg = ((const float4*)g)[tid];
    const float4 bb = ((const float4*)be)[tid];
    float o[4];
    o[0] = (v.x - mu) * rs * gg.x + bb.x;
    o[1] = (v.y - mu) * rs * gg.y + bb.y;
    o[2] = (v.z - mu) * rs * gg.z + bb.z;
    o[3] = (v.w - mu) * rs * gg.w + bb.w;
    if (sizeof(TOUT) == 4) {
        float4 of = {o[0], o[1], o[2], o[3]};
        ((float4*)((float*)Y + (size_t)row * DD))[tid] = of;
    } else {
        ushort4 p;
        p.x = f2bf_rne(o[0]); p.y = f2bf_rne(o[1]);
        p.z = f2bf_rne(o[2]); p.w = f2bf_rne(o[3]);
        ((ushort4*)((unsigned short*)Y + (size_t)row * DD))[tid] = p;
    }
}

extern "C" void kernel_launch(void* const* d_in, const int* in_sizes, int n_in,
                              void* d_out, int out_size, void* d_ws, size_t ws_size,
                              hipStream_t stream) {
    const float* x = (const float*)d_in[0];
    const float* Wq = (const float*)d_in[1];
    const float* Wk = (const float*)d_in[2];
    const float* Wv = (const float*)d_in[3];
    const float* Wo = (const float*)d_in[4];
    const float* g1 = (const float*)d_in[5];
    const float* be1 = (const float*)d_in[6];
    const float* w_in = (const float*)d_in[7];
    const float* b_in = (const float*)d_in[8];
    const float* w_out = (const float*)d_in[9];
    const float* b_out = (const float*)d_in[10];
    const float* g2 = (const float*)d_in[11];
    const float* be2 = (const float*)d_in[12];
    float* out = (float*)d_out;

    // Workspace (bytes), peak 120 MiB. DISJOINTNESS AUDIT (unchanged):
    //   Prep:     reads x,weights          -> writes xb[64,80), WqkvT[96,102),
    //                                         WoT[102,104), w_inT[104,112), w_outT[112,120)
    //   QKV:      reads xb,WqkvT           -> writes Qb[0,16) Kb[16,32) VT[32,48)
    //   attn:     reads Qb,Kb,VT           -> writes At[48,64)
    //   Wo-GEMM:  reads At,WoT,xb          -> writes X1b[80,96)   (EPI 7, bf16)
    //   LN1:      in-place X1b[80,96)
    //   FFN1:     reads X1b,w_inT          -> writes Hd[0,64)     (Qb/Kb/VT/At dead)
    //   FFN2:     reads Hd,X1b,w_outT      -> writes X2b[64,80)   (xb dead)
    //   LN2:      reads X2b                -> writes d_out
    char* wsb = (char*)d_ws;
    const size_t MiB = 1u << 20;
    bf16* Qb = (bf16*)(wsb);
    bf16* Kb = (bf16*)(wsb + 16 * MiB);
    bf16* VT = (bf16*)(wsb + 32 * MiB);
    bf16* At = (bf16*)(wsb + 48 * MiB);
    bf16* xb = (bf16*)(wsb + 64 * MiB);
    bf16* X1b = (bf16*)(wsb + 80 * MiB);
    bf16* Hd = (bf16*)(wsb);
    bf16* X2b = (bf16*)(wsb + 64 * MiB);
    bf16* WqkvT = (bf16*)(wsb + 96 * MiB);
    bf16* WoT = (bf16*)(wsb + 102 * MiB);
    bf16* w_inT = (bf16*)(wsb + 104 * MiB);
    bf16* w_outT = (bf16*)(wsb + 112 * MiB);
    (void)ws_size;

    const int M = BB * SS;  // 8192
    dim3 blk(256);
    dim3 blk512(512);

    // ---- Fused prep: x->bf16 + all weight transposes (one launch) ----
    prep_kernel<<<dim3(8192 + 3072 + 1024 + 4096 + 4096), blk, 0, stream>>>(
        x, Wq, Wk, Wv, Wo, w_in, w_out, xb, WqkvT, WoT, w_inT, w_outT);

    // ---- Fused QKV: xb @ [Wq|Wk|Wv]; 256x256 tiles, 12x32 = 384 blocks ----
    gemm8w<256, 2, 4, 5><<<dim3(3 * DD / 256, M / 256), blk512, 0, stream>>>(
        xb, WqkvT, Qb, nullptr, nullptr, Kb, VT, M, 3 * DD, DD, QSCALE);

    // ---- MFMA causal flash attention ----
    attn_mfma<<<dim3(BB * HH, SS / 64), blk, 0, stream>>>(Qb, Kb, VT, At);

    // ---- attn(view) @ Wo + xb -> X1b bf16 (EPI 7); proven 128^2 kernel ----
    mfma_gemm<bf16, bf16, 7><<<dim3(DD / 128, M / 128), blk, 0, stream>>>(
        At, WoT, X1b, nullptr, xb, nullptr, nullptr, M, DD, DD, 1.0f);
    // LN1 in-place (bf16 -> bf16)
    ln_kernel<bf16, bf16><<<dim3(M), blk, 0, stream>>>(X1b, X1b, g1, be1);

    // ---- FFN1: relu(X1b @ w_in + b_in); 256x256 tiles, 16x32 = 512 blocks ----
    gemm8w<256, 2, 4, 2><<<dim3(FF / 256, M / 256), blk512, 0, stream>>>(
        X1b, w_inT, Hd, b_in, nullptr, nullptr, nullptr, M, FF, DD, 1.0f);

    // ---- FFN2: Hd @ w_out + b_out + X1b; 256x128 tiles, 8x32 = 256 blocks ----
    gemm8w<128, 4, 2, 6><<<dim3(DD / 128, M / 256), blk512, 0, stream>>>(
        Hd, w_outT, X2b, b_out, X1b, nullptr, nullptr, M, DD, FF, 1.0f);

    // ---- LN2: X2b bf16 -> fp32 out ----
    ln_kernel<bf16, float><<<dim3(M), blk, 0, stream>>>(X2b, out, g2, be2);
}

// Round 4
// 463.923 us; speedup vs baseline: 1.1524x; 1.1524x over previous
//
#include <hip/hip_runtime.h>
#include <hip/hip_bf16.h>

typedef __hip_bfloat16 bf16;

#define BB 4
#define SS 2048
#define DD 1024
#define HH 16
#define FF 4096
#define HD 64
#define LN_EPS 1e-5f
#define QSCALE 0.1803368801111204f  // 0.125 * log2(e): softmax in exp2 domain

typedef __attribute__((ext_vector_type(8))) __bf16 bf16x8;
typedef __attribute__((ext_vector_type(8))) unsigned short u16x8;
typedef __attribute__((ext_vector_type(4))) float f32x4;

__device__ __forceinline__ float cvt(float v) { return v; }
__device__ __forceinline__ float cvt(bf16 v) { return __bfloat162float(v); }
__device__ __forceinline__ void stf(float* p, float v) { *p = v; }
__device__ __forceinline__ void stf(bf16* p, float v) { *p = __float2bfloat16(v); }

// fp32 -> bf16 round-to-nearest-even
__device__ __forceinline__ unsigned short f2bf_rne(float x) {
    unsigned int u = __float_as_uint(x);
    unsigned int r = (u + 0x7fffu + ((u >> 16) & 1u)) >> 16;
    return (unsigned short)r;
}

// async global->LDS, 16B/lane; LDS dest lane-contiguous (m104/m108).
// Global-side address carries the XOR swizzle (measured 0 conflicts).
__device__ __forceinline__ void async_cp16(const void* g, void* l) {
    __builtin_amdgcn_global_load_lds(
        (const __attribute__((address_space(1))) unsigned int*)g,
        (__attribute__((address_space(3))) unsigned int*)l, 16, 0, 0);
}

__device__ __forceinline__ u16x8 ld_f32_chunk(const float* p) {
    const float4* q = (const float4*)p;
    const float4 a = q[0], b = q[1];
    u16x8 r;
    r[0] = f2bf_rne(a.x); r[1] = f2bf_rne(a.y); r[2] = f2bf_rne(a.z); r[3] = f2bf_rne(a.w);
    r[4] = f2bf_rne(b.x); r[5] = f2bf_rne(b.y); r[6] = f2bf_rne(b.z); r[7] = f2bf_rne(b.w);
    return r;
}

// ---------------------------------------------------------------------------
// MFMA GEMM: C(MxN) = A(MxK) @ B(KxN), B supplied TRANSPOSED (N x K bf16).
// 128x128 tile, BK=64, 4 waves, 16x16x32 bf16 MFMA. LDS XOR-swizzled via the
// GLOBAL fetch index (slot c of row r holds chunk c^(r&7)); reads 2-way max.
// R14: XCD swizzle with 2D sub-band visitation. XCD = orig_id % 8 owns a
// contiguous by-band (gy/8 rows x all bx). Within the chunk, ids sweep
// BW-column sub-bands: co-resident window = 8by x BWbx, working set
// (8 A-panels + BW B-panels) sized to FIT the 4 MiB per-XCD L2, and the
// chunk's A-panels stay L2-resident across all sub-bands. BW=gx reduces to
// the R1 row-major mapping exactly (used for narrow-N GEMMs where A-reuse
// dominates). Requires gy%8==0 and gx%BW==0 (all launches satisfy).
// EPI 0: C = gemm*oscale (bf16)        EPI 2: C = relu(gemm+bias) (bf16)
// EPI 5: fused QKV: cols [0,1k)->C (bf16, *oscale); [1k,2k)->C2 (bf16);
//        [2k,3k)->C3 transposed VT(B*D,S) write.
// EPI 6: C = gemm + bias + res_bf (bf16)   EPI 7: C = gemm + res_bf (bf16)
// ---------------------------------------------------------------------------
template <typename TA, typename TC, int EPI, int BW>
__launch_bounds__(256)
__global__ void mfma_gemm(const TA* __restrict__ A, const bf16* __restrict__ Bt,
                          TC* __restrict__ C, const float* __restrict__ bias,
                          const bf16* __restrict__ resb,
                          bf16* __restrict__ C2, bf16* __restrict__ C3,
                          int M, int N, int K, float oscale) {
    constexpr bool AF = (sizeof(TA) == 4);  // fp32 A path (register staging)
    __shared__ unsigned short As[128 * 64];
    __shared__ unsigned short Bs[128 * 64];

    const int tid = threadIdx.x;
    const int lane = tid & 63;
    const int w = tid >> 6;
    const int wm = w >> 1, wn = w & 1;

    // ---- XCD-chunked 2D sub-band swizzle (T1 + L2-window shaping). ----
    const int gx = gridDim.x, gy = gridDim.y;
    const int id = blockIdx.y * gx + blockIdx.x;
    const int R = gy >> 3;                 // chunk rows per XCD (gy%8==0)
    const int k = id & 7;                  // HW: XCD = orig_id % 8
    const int j = id >> 3;                 // index within XCD chunk
    const int sbs = R * BW;                // ids per sub-band
    const int sb = j / sbs;
    const int rem = j % sbs;
    const int by = k * R + rem / BW;
    const int bx = sb * BW + rem % BW;
    const int m0 = by * 128, n0 = bx * 128;

    int ff[4], fr[4], fc[4], fg[4];
#pragma unroll
    for (int i = 0; i < 4; ++i) {
        ff[i] = tid + i * 256;
        fr[i] = ff[i] >> 3;
        fc[i] = ff[i] & 7;
        fg[i] = fc[i] ^ (fr[i] & 7);
    }

    f32x4 acc[4][4];
#pragma unroll
    for (int i = 0; i < 4; ++i)
#pragma unroll
        for (int j2 = 0; j2 < 4; ++j2) acc[i][j2] = (f32x4){0.f, 0.f, 0.f, 0.f};

    u16x8 sa[4];
    if (AF) {
#pragma unroll
        for (int i = 0; i < 4; ++i)
            sa[i] = ld_f32_chunk((const float*)A + (size_t)(m0 + fr[i]) * K + fg[i] * 8);
    }

    for (int k0 = 0; k0 < K; k0 += 64) {
        if (k0 > 0) __syncthreads();
        if (AF) {
#pragma unroll
            for (int i = 0; i < 4; ++i)
                *(u16x8*)&As[ff[i] * 8] = sa[i];
        } else {
#pragma unroll
            for (int i = 0; i < 4; ++i)
                async_cp16((const unsigned short*)A + (size_t)(m0 + fr[i]) * K + k0 + fg[i] * 8,
                           &As[ff[i] * 8]);
        }
#pragma unroll
        for (int i = 0; i < 4; ++i)
            async_cp16((const unsigned short*)Bt + (size_t)(n0 + fr[i]) * K + k0 + fg[i] * 8,
                       &Bs[ff[i] * 8]);
        __syncthreads();

        if (AF && k0 + 64 < K) {
            const int kn = k0 + 64;
#pragma unroll
            for (int i = 0; i < 4; ++i)
                sa[i] = ld_f32_chunk((const float*)A + (size_t)(m0 + fr[i]) * K + kn + fg[i] * 8);
        }

#pragma unroll
        for (int ks = 0; ks < 2; ++ks) {
            bf16x8 af[4], bfr[4];
#pragma unroll
            for (int i = 0; i < 4; ++i) {
                const int row = wm * 64 + i * 16 + (lane & 15);
                const int col = wn * 64 + i * 16 + (lane & 15);
                const int g = ks * 4 + (lane >> 4);
                af[i]  = *(const bf16x8*)&As[row * 64 + (g ^ (row & 7)) * 8];
                bfr[i] = *(const bf16x8*)&Bs[col * 64 + (g ^ (col & 7)) * 8];
            }
#pragma unroll
            for (int i = 0; i < 4; ++i)
#pragma unroll
                for (int j2 = 0; j2 < 4; ++j2)
                    acc[i][j2] = __builtin_amdgcn_mfma_f32_16x16x32_bf16(
                        af[i], bfr[j2], acc[i][j2], 0, 0, 0);
        }
    }

    // Epilogue. C/D layout: col = lane&15, row = (lane>>4)*4 + reg.
#pragma unroll
    for (int i = 0; i < 4; ++i) {
        const int mrow0 = m0 + wm * 64 + i * 16 + (lane >> 4) * 4;
#pragma unroll
        for (int j2 = 0; j2 < 4; ++j2) {
            const int n = n0 + wn * 64 + j2 * 16 + (lane & 15);
            if (EPI == 5) {
                const int reg = n >> 10;  // tile-uniform: 0=Q, 1=K, 2=V
                const int nn = n & 1023;
                if (reg == 0) {
#pragma unroll
                    for (int r = 0; r < 4; ++r)
                        stf((bf16*)C + (size_t)(mrow0 + r) * 1024 + nn, acc[i][j2][r] * oscale);
                } else if (reg == 1) {
#pragma unroll
                    for (int r = 0; r < 4; ++r)
                        stf(C2 + (size_t)(mrow0 + r) * 1024 + nn, acc[i][j2][r]);
                } else {
                    const int bb = mrow0 >> 11, s = mrow0 & 2047;
                    ushort4 pk;
                    pk.x = f2bf_rne(acc[i][j2][0]);
                    pk.y = f2bf_rne(acc[i][j2][1]);
                    pk.z = f2bf_rne(acc[i][j2][2]);
                    pk.w = f2bf_rne(acc[i][j2][3]);
                    *(ushort4*)((unsigned short*)C3 + ((size_t)bb * 1024 + nn) * SS + s) = pk;
                }
            } else {
#pragma unroll
                for (int r = 0; r < 4; ++r) {
                    const size_t idx = (size_t)(mrow0 + r) * N + n;
                    float v = acc[i][j2][r];
                    if (EPI == 0) v *= oscale;
                    if (EPI == 2) { v += bias[n]; v = fmaxf(v, 0.0f); }
                    if (EPI == 6) v += bias[n] + cvt(resb[idx]);
                    if (EPI == 7) v += cvt(resb[idx]);
                    stf(&C[idx], v);
                }
            }
        }
    }
}

// ---------------------------------------------------------------------------
// Fused prep: one launch handles x->bf16 convert + ALL weight transposes.
// Block id segments:
//   [0, 8192)          : x -> xb convert (1024 floats/block)
//   [8192, 8192+3072)  : QKV per-head transpose (z=wi*16+head, 2x32 tiles)
//   [+3072, +1024)     : Wo (1024x1024)
//   [+1024, +4096)     : w_in (1024x4096)
//   [+4096, +4096)     : w_out (4096x1024)
// All transposes: fp32 (R x C) tile-transposed to bf16 (C x R).
// ---------------------------------------------------------------------------
__launch_bounds__(256)
__global__ void prep_kernel(const float* __restrict__ x,
                            const float* __restrict__ Wq, const float* __restrict__ Wk,
                            const float* __restrict__ Wv, const float* __restrict__ Wo,
                            const float* __restrict__ w_in, const float* __restrict__ w_out,
                            bf16* __restrict__ xb, bf16* __restrict__ WqkvT,
                            bf16* __restrict__ WoT, bf16* __restrict__ w_inT,
                            bf16* __restrict__ w_outT) {
    const int id = blockIdx.x;
    if (id < 8192) {
        const int i = id * 256 + threadIdx.x;
        const float4 v = ((const float4*)x)[i];
        ushort4 p;
        p.x = f2bf_rne(v.x); p.y = f2bf_rne(v.y); p.z = f2bf_rne(v.z); p.w = f2bf_rne(v.w);
        ((ushort4*)xb)[i] = p;
        return;
    }
    __shared__ float t[32][33];
    const int rem = id - 8192;
    const float* in;
    bf16* out;
    int R, C, bx, by;
    size_t in_o = 0, out_o = 0;
    if (rem < 3072) {
        const int z = rem >> 6, r2 = rem & 63;
        const int wi = z >> 4, head = z & 15;
        in = (wi == 0) ? Wq : (wi == 1) ? Wk : Wv;
        in_o = (size_t)head * DD * HD;
        out = WqkvT;
        out_o = (size_t)wi * DD * DD + (size_t)head * HD * DD;
        R = DD; C = HD;
        bx = (r2 & 1) * 32; by = (r2 >> 1) * 32;
    } else if (rem < 3072 + 1024) {
        const int r2 = rem - 3072;
        in = Wo; out = WoT; R = DD; C = DD;
        bx = (r2 & 31) * 32; by = (r2 >> 5) * 32;
    } else if (rem < 3072 + 1024 + 4096) {
        const int r2 = rem - 3072 - 1024;
        in = w_in; out = w_inT; R = DD; C = FF;
        bx = (r2 & 127) * 32; by = (r2 >> 7) * 32;
    } else {
        const int r2 = rem - 3072 - 1024 - 4096;
        in = w_out; out = w_outT; R = FF; C = DD;
        bx = (r2 & 31) * 32; by = (r2 >> 5) * 32;
    }
    const int tx = threadIdx.x & 31, ty = threadIdx.x >> 5;
#pragma unroll
    for (int i = 0; i < 32; i += 8)
        t[ty + i][tx] = in[in_o + (size_t)(by + ty + i) * C + bx + tx];
    __syncthreads();
#pragma unroll
    for (int i = 0; i < 32; i += 8)
        out[out_o + (size_t)(bx + ty + i) * R + by + tx] = __float2bfloat16(t[tx][ty + i]);
}

// ---------------------------------------------------------------------------
// MFMA causal flash attention (proven config — 64-key tiles):
// fixed-base exp2 softmax (no running max; xavier-bounded scores), lane-local
// l accumulation with ONE end reduction; K/V async-staged with global-side
// XOR swizzle; P C->A layout via padded LDS (stride 72).
// ---------------------------------------------------------------------------
__launch_bounds__(256, 4)
__global__ void attn_mfma(const bf16* __restrict__ Q, const bf16* __restrict__ K,
                          const bf16* __restrict__ VT, bf16* __restrict__ O) {
    __shared__ unsigned short Ks[64 * 64];
    __shared__ unsigned short Vs[64 * 64];
    __shared__ unsigned short Ps[64 * 72];

    const int tid = threadIdx.x;
    const int lane = tid & 63;
    const int w = tid >> 6;
    const int ln = lane & 15;
    const int qd = lane >> 4;
    const int bh = blockIdx.x;
    const int b = bh >> 4;
    const int h = bh & 15;
    const int qi = 31 - blockIdx.y;  // heavy blocks dispatch first
    const int q0 = qi * 64;

    bf16x8 aq[2];
    {
        const unsigned short* qp =
            (const unsigned short*)Q + ((size_t)b * SS + q0 + w * 16 + ln) * DD + h * HD;
        aq[0] = *(const bf16x8*)(qp + qd * 8);
        aq[1] = *(const bf16x8*)(qp + 32 + qd * 8);
    }

    int sf[2], sr[2], sg[2];
#pragma unroll
    for (int i = 0; i < 2; ++i) {
        sf[i] = tid + i * 256;
        sr[i] = sf[i] >> 3;
        sg[i] = (sf[i] & 7) ^ (sr[i] & 7);
    }
    const unsigned short* kbase = (const unsigned short*)K + (size_t)b * SS * DD + h * HD;
    const unsigned short* vbase = (const unsigned short*)VT + (size_t)(b * DD + h * HD) * SS;

    f32x4 oacc[4];
#pragma unroll
    for (int e = 0; e < 4; ++e) oacc[e] = (f32x4){0.f, 0.f, 0.f, 0.f};
    float l_r[4] = {0.f, 0.f, 0.f, 0.f};

    for (int kt = 0; kt <= qi; ++kt) {
        const int t0 = kt * 64;
        __syncthreads();
#pragma unroll
        for (int i = 0; i < 2; ++i) {
            async_cp16(kbase + (size_t)(t0 + sr[i]) * DD + sg[i] * 8, &Ks[sf[i] * 8]);
            async_cp16(vbase + (size_t)sr[i] * SS + t0 + sg[i] * 8, &Vs[sf[i] * 8]);
        }
        __syncthreads();

        // ---- scores (exp2 domain) ----
        f32x4 sfr[4];
#pragma unroll
        for (int ct = 0; ct < 4; ++ct) {
            const int row = ct * 16 + ln;
            const bf16x8 b0 = *(const bf16x8*)&Ks[row * 64 + ((qd) ^ (row & 7)) * 8];
            const bf16x8 b1 = *(const bf16x8*)&Ks[row * 64 + ((4 + qd) ^ (row & 7)) * 8];
            f32x4 t = __builtin_amdgcn_mfma_f32_16x16x32_bf16(
                aq[0], b0, (f32x4){0.f, 0.f, 0.f, 0.f}, 0, 0, 0);
            sfr[ct] = __builtin_amdgcn_mfma_f32_16x16x32_bf16(aq[1], b1, t, 0, 0, 0);
        }

        // ---- causal mask (diagonal tile only): exp2(-1e30) = 0 ----
        if (kt == qi) {
#pragma unroll
            for (int ct = 0; ct < 4; ++ct) {
                const int tg = t0 + ct * 16 + ln;
#pragma unroll
                for (int r = 0; r < 4; ++r) {
                    const int qg = q0 + w * 16 + qd * 4 + r;
                    if (tg > qg) sfr[ct][r] = -1e30f;
                }
            }
        }

        // ---- p = exp2(s); lane-local l accumulation ----
#pragma unroll
        for (int ct = 0; ct < 4; ++ct)
#pragma unroll
            for (int r = 0; r < 4; ++r)
                sfr[ct][r] = __builtin_amdgcn_exp2f(sfr[ct][r]);
#pragma unroll
        for (int r = 0; r < 4; ++r)
            l_r[r] += (sfr[0][r] + sfr[1][r]) + (sfr[2][r] + sfr[3][r]);

        // ---- P: C-layout -> LDS -> A-layout ----
#pragma unroll
        for (int ct = 0; ct < 4; ++ct)
#pragma unroll
            for (int r = 0; r < 4; ++r)
                Ps[(w * 16 + qd * 4 + r) * 72 + ct * 16 + ln] = f2bf_rne(sfr[ct][r]);
        const bf16x8 ap0 = *(const bf16x8*)&Ps[(w * 16 + ln) * 72 + qd * 8];
        const bf16x8 ap1 = *(const bf16x8*)&Ps[(w * 16 + ln) * 72 + 32 + qd * 8];

        // ---- O += P @ V (no rescale) ----
#pragma unroll
        for (int et = 0; et < 4; ++et) {
            const int row = et * 16 + ln;
            const bf16x8 v0 = *(const bf16x8*)&Vs[row * 64 + ((qd) ^ (row & 7)) * 8];
            const bf16x8 v1 = *(const bf16x8*)&Vs[row * 64 + ((4 + qd) ^ (row & 7)) * 8];
            oacc[et] = __builtin_amdgcn_mfma_f32_16x16x32_bf16(ap0, v0, oacc[et], 0, 0, 0);
            oacc[et] = __builtin_amdgcn_mfma_f32_16x16x32_bf16(ap1, v1, oacc[et], 0, 0, 0);
        }
    }

    // ---- ONE l reduction across the 16-lane col group, then finalize ----
#pragma unroll
    for (int st = 1; st <= 8; st <<= 1)
#pragma unroll
        for (int r = 0; r < 4; ++r)
            l_r[r] += __shfl_xor(l_r[r], st);
    float linv[4];
#pragma unroll
    for (int r = 0; r < 4; ++r) linv[r] = 1.0f / l_r[r];
    unsigned short* ob = (unsigned short*)O + (size_t)bh * SS * HD;
#pragma unroll
    for (int et = 0; et < 4; ++et)
#pragma unroll
        for (int r = 0; r < 4; ++r) {
            const int qg = q0 + w * 16 + qd * 4 + r;
            ob[(size_t)qg * HD + et * 16 + ln] = f2bf_rne(oacc[et][r] * linv[r]);
        }
}

// ---------------------------------------------------------------------------
// LayerNorm over D=1024, templated in/out dtype, fused shuffle reduction.
// In-place safe (each thread reads its 4 elems before any write).
// ---------------------------------------------------------------------------
template <typename TIN, typename TOUT>
__launch_bounds__(256)
__global__ void ln_kernel(const TIN* __restrict__ X, TOUT* __restrict__ Y,
                          const float* __restrict__ g, const float* __restrict__ be) {
    const int row = blockIdx.x;
    const int tid = threadIdx.x;
    const int lane = tid & 63, w = tid >> 6;
    __shared__ float red[8];
    __shared__ float mv[2];

    float4 v;
    if (sizeof(TIN) == 4) {
        v = ((const float4*)((const float*)X + (size_t)row * DD))[tid];
    } else {
        const ushort4 u = ((const ushort4*)((const unsigned short*)X + (size_t)row * DD))[tid];
        v.x = __uint_as_float((unsigned)u.x << 16);
        v.y = __uint_as_float((unsigned)u.y << 16);
        v.z = __uint_as_float((unsigned)u.z << 16);
        v.w = __uint_as_float((unsigned)u.w << 16);
    }
    float s = (v.x + v.y) + (v.z + v.w);
    float q = (v.x * v.x + v.y * v.y) + (v.z * v.z + v.w * v.w);
#pragma unroll
    for (int st = 1; st < 64; st <<= 1) {
        s += __shfl_xor(s, st);
        q += __shfl_xor(q, st);
    }
    if (lane == 0) { red[w] = s; red[4 + w] = q; }
    __syncthreads();
    if (tid == 0) {
        const float ts = (red[0] + red[1]) + (red[2] + red[3]);
        const float tq = (red[4] + red[5]) + (red[6] + red[7]);
        const float mu = ts * (1.0f / DD);
        mv[0] = mu;
        mv[1] = rsqrtf(tq * (1.0f / DD) - mu * mu + LN_EPS);
    }
    __syncthreads();
    const float mu = mv[0], rs = mv[1];
    const float4 gg = ((const float4*)g)[tid];
    const float4 bb = ((const float4*)be)[tid];
    float o[4];
    o[0] = (v.x - mu) * rs * gg.x + bb.x;
    o[1] = (v.y - mu) * rs * gg.y + bb.y;
    o[2] = (v.z - mu) * rs * gg.z + bb.z;
    o[3] = (v.w - mu) * rs * gg.w + bb.w;
    if (sizeof(TOUT) == 4) {
        float4 of = {o[0], o[1], o[2], o[3]};
        ((float4*)((float*)Y + (size_t)row * DD))[tid] = of;
    } else {
        ushort4 p;
        p.x = f2bf_rne(o[0]); p.y = f2bf_rne(o[1]);
        p.z = f2bf_rne(o[2]); p.w = f2bf_rne(o[3]);
        ((ushort4*)((unsigned short*)Y + (size_t)row * DD))[tid] = p;
    }
}

extern "C" void kernel_launch(void* const* d_in, const int* in_sizes, int n_in,
                              void* d_out, int out_size, void* d_ws, size_t ws_size,
                              hipStream_t stream) {
    const float* x = (const float*)d_in[0];
    const float* Wq = (const float*)d_in[1];
    const float* Wk = (const float*)d_in[2];
    const float* Wv = (const float*)d_in[3];
    const float* Wo = (const float*)d_in[4];
    const float* g1 = (const float*)d_in[5];
    const float* be1 = (const float*)d_in[6];
    const float* w_in = (const float*)d_in[7];
    const float* b_in = (const float*)d_in[8];
    const float* w_out = (const float*)d_in[9];
    const float* b_out = (const float*)d_in[10];
    const float* g2 = (const float*)d_in[11];
    const float* be2 = (const float*)d_in[12];
    float* out = (float*)d_out;

    // Workspace (bytes), peak 120 MiB. DISJOINTNESS AUDIT (unchanged):
    //   Prep:     reads x,weights          -> writes xb[64,80), WqkvT[96,102),
    //                                         WoT[102,104), w_inT[104,112), w_outT[112,120)
    //   QKV:      reads xb,WqkvT           -> writes Qb[0,16) Kb[16,32) VT[32,48)
    //   attn:     reads Qb,Kb,VT           -> writes At[48,64)
    //   Wo-GEMM:  reads At,WoT,xb          -> writes X1b[80,96)   (EPI 7, bf16)
    //   LN1:      in-place X1b[80,96)
    //   FFN1:     reads X1b,w_inT          -> writes Hd[0,64)     (Qb/Kb/VT/At dead)
    //   FFN2:     reads Hd,X1b,w_outT      -> writes X2b[64,80)   (xb dead)
    //   LN2:      reads X2b                -> writes d_out
    char* wsb = (char*)d_ws;
    const size_t MiB = 1u << 20;
    bf16* Qb = (bf16*)(wsb);
    bf16* Kb = (bf16*)(wsb + 16 * MiB);
    bf16* VT = (bf16*)(wsb + 32 * MiB);
    bf16* At = (bf16*)(wsb + 48 * MiB);
    bf16* xb = (bf16*)(wsb + 64 * MiB);
    bf16* X1b = (bf16*)(wsb + 80 * MiB);
    bf16* Hd = (bf16*)(wsb);
    bf16* X2b = (bf16*)(wsb + 64 * MiB);
    bf16* WqkvT = (bf16*)(wsb + 96 * MiB);
    bf16* WoT = (bf16*)(wsb + 102 * MiB);
    bf16* w_inT = (bf16*)(wsb + 104 * MiB);
    bf16* w_outT = (bf16*)(wsb + 112 * MiB);
    (void)ws_size;

    const int M = BB * SS;  // 8192
    dim3 blk(256);

    // ---- Fused prep: x->bf16 + all weight transposes (one launch) ----
    prep_kernel<<<dim3(8192 + 3072 + 1024 + 4096 + 4096), blk, 0, stream>>>(
        x, Wq, Wk, Wv, Wo, w_in, w_out, xb, WqkvT, WoT, w_inT, w_outT);

    // ---- Fused QKV: xb @ [Wq|Wk|Wv] -> Qb(*QSCALE), Kb, VT ----
    // gx=24: BW=4 sub-bands -> window 8by x 4bx = 2M A + 1M B < L2.
    mfma_gemm<bf16, bf16, 5, 4><<<dim3(3 * DD / 128, M / 128), blk, 0, stream>>>(
        xb, WqkvT, Qb, nullptr, nullptr, Kb, VT, M, 3 * DD, DD, QSCALE);

    // ---- MFMA causal flash attention (fixed-base exp2, 64-key tiles) ----
    attn_mfma<<<dim3(BB * HH, SS / 64), blk, 0, stream>>>(Qb, Kb, VT, At);

    // ---- attn(view) @ Wo + xb -> X1b bf16 (EPI 7); gx=8: BW=8 == R1 map ----
    mfma_gemm<bf16, bf16, 7, 8><<<dim3(DD / 128, M / 128), blk, 0, stream>>>(
        At, WoT, X1b, nullptr, xb, nullptr, nullptr, M, DD, DD, 1.0f);
    // LN1 in-place (bf16 -> bf16)
    ln_kernel<bf16, bf16><<<dim3(M), blk, 0, stream>>>(X1b, X1b, g1, be1);

    // ---- FFN1: relu(X1b @ w_in + b_in) -> Hd bf16; gx=32: BW=4 windows ----
    mfma_gemm<bf16, bf16, 2, 4><<<dim3(FF / 128, M / 128), blk, 0, stream>>>(
        X1b, w_inT, Hd, b_in, nullptr, nullptr, nullptr, M, FF, DD, 1.0f);

    // ---- FFN2: Hd @ w_out + b_out + X1b -> X2b; gx=8: BW=8 == R1 map ----
    mfma_gemm<bf16, bf16, 6, 8><<<dim3(DD / 128, M / 128), blk, 0, stream>>>(
        Hd, w_outT, X2b, b_out, X1b, nullptr, nullptr, M, DD, FF, 1.0f);

    // ---- LN2: X2b bf16 -> fp32 out ----
    ln_kernel<bf16, float><<<dim3(M), blk, 0, stream>>>(X2b, out, g2, be2);
}

// Round 5
// 446.341 us; speedup vs baseline: 1.1978x; 1.0394x over previous
//
#include <hip/hip_runtime.h>
#include <hip/hip_bf16.h>

typedef __hip_bfloat16 bf16;

#define BB 4
#define SS 2048
#define DD 1024
#define HH 16
#define FF 4096
#define HD 64
#define LN_EPS 1e-5f
#define QSCALE 0.1803368801111204f  // 0.125 * log2(e): softmax in exp2 domain

typedef __attribute__((ext_vector_type(8))) __bf16 bf16x8;
typedef __attribute__((ext_vector_type(8))) unsigned short u16x8;
typedef __attribute__((ext_vector_type(4))) float f32x4;

__device__ __forceinline__ float cvt(float v) { return v; }
__device__ __forceinline__ float cvt(bf16 v) { return __bfloat162float(v); }
__device__ __forceinline__ void stf(float* p, float v) { *p = v; }
__device__ __forceinline__ void stf(bf16* p, float v) { *p = __float2bfloat16(v); }

// fp32 -> bf16 round-to-nearest-even
__device__ __forceinline__ unsigned short f2bf_rne(float x) {
    unsigned int u = __float_as_uint(x);
    unsigned int r = (u + 0x7fffu + ((u >> 16) & 1u)) >> 16;
    return (unsigned short)r;
}

// async global->LDS, 16B/lane; LDS dest lane-contiguous (m104/m108).
// Global-side address carries the XOR swizzle (measured 0 conflicts).
__device__ __forceinline__ void async_cp16(const void* g, void* l) {
    __builtin_amdgcn_global_load_lds(
        (const __attribute__((address_space(1))) unsigned int*)g,
        (__attribute__((address_space(3))) unsigned int*)l, 16, 0, 0);
}

// Counted vmcnt wait: lets N loads stay in flight across the barrier (T4).
template <int N>
__device__ __forceinline__ void s_wait_vmcnt() {
    asm volatile("s_waitcnt vmcnt(%0)" ::"n"(N) : "memory");
    __builtin_amdgcn_sched_barrier(0);
}

// Raw workgroup barrier WITHOUT the __syncthreads vmcnt(0) drain.
__device__ __forceinline__ void sync_raw() {
    asm volatile("" ::: "memory");
    __builtin_amdgcn_s_barrier();
    asm volatile("" ::: "memory");
    __builtin_amdgcn_sched_barrier(0);
}

__device__ __forceinline__ u16x8 ld_f32_chunk(const float* p) {
    const float4* q = (const float4*)p;
    const float4 a = q[0], b = q[1];
    u16x8 r;
    r[0] = f2bf_rne(a.x); r[1] = f2bf_rne(a.y); r[2] = f2bf_rne(a.z); r[3] = f2bf_rne(a.w);
    r[4] = f2bf_rne(b.x); r[5] = f2bf_rne(b.y); r[6] = f2bf_rne(b.z); r[7] = f2bf_rne(b.w);
    return r;
}

// ---------------------------------------------------------------------------
// MFMA GEMM: C(MxN) = A(MxK) @ B(KxN), B supplied TRANSPOSED (N x K bf16).
// 128x128 tile, BK=64, 4 waves, 16x16x32 bf16 MFMA. LDS XOR-swizzled via the
// GLOBAL fetch index (slot c of row r holds chunk c^(r&7)); reads 2-way max.
// XCD swizzle with 2D sub-band visitation (BW columns per band). BW=gx
// reduces to the R1 row-major mapping. R5 MEASURED NOTE: FFN1 at BW=4 halved
// FETCH (139.6->65.6 MB) but COST +8.4us -> fetch is not on the critical
// path at 2 blocks/CU; FFN1 pinned back to BW=gx. QKV keeps BW=4 (net win).
// EPI 0: C = gemm*oscale (bf16)        EPI 2: C = relu(gemm+bias) (bf16)
// EPI 5: fused QKV: cols [0,1k)->C (bf16, *oscale); [1k,2k)->C2 (bf16);
//        [2k,3k)->C3 transposed VT(B*D,S) write.
// EPI 6: C = gemm + bias + res_bf (bf16)   EPI 7: C = gemm + res_bf (bf16)
// ---------------------------------------------------------------------------
template <typename TA, typename TC, int EPI, int BW>
__launch_bounds__(256)
__global__ void mfma_gemm(const TA* __restrict__ A, const bf16* __restrict__ Bt,
                          TC* __restrict__ C, const float* __restrict__ bias,
                          const bf16* __restrict__ resb,
                          bf16* __restrict__ C2, bf16* __restrict__ C3,
                          int M, int N, int K, float oscale) {
    constexpr bool AF = (sizeof(TA) == 4);  // fp32 A path (register staging)
    __shared__ unsigned short As[128 * 64];
    __shared__ unsigned short Bs[128 * 64];

    const int tid = threadIdx.x;
    const int lane = tid & 63;
    const int w = tid >> 6;
    const int wm = w >> 1, wn = w & 1;

    // ---- XCD-chunked 2D sub-band swizzle (T1 + L2-window shaping). ----
    const int gx = gridDim.x, gy = gridDim.y;
    const int id = blockIdx.y * gx + blockIdx.x;
    const int R = gy >> 3;                 // chunk rows per XCD (gy%8==0)
    const int k = id & 7;                  // HW: XCD = orig_id % 8
    const int j = id >> 3;                 // index within XCD chunk
    const int sbs = R * BW;                // ids per sub-band
    const int sb = j / sbs;
    const int rem = j % sbs;
    const int by = k * R + rem / BW;
    const int bx = sb * BW + rem % BW;
    const int m0 = by * 128, n0 = bx * 128;

    int ff[4], fr[4], fc[4], fg[4];
#pragma unroll
    for (int i = 0; i < 4; ++i) {
        ff[i] = tid + i * 256;
        fr[i] = ff[i] >> 3;
        fc[i] = ff[i] & 7;
        fg[i] = fc[i] ^ (fr[i] & 7);
    }

    f32x4 acc[4][4];
#pragma unroll
    for (int i = 0; i < 4; ++i)
#pragma unroll
        for (int j2 = 0; j2 < 4; ++j2) acc[i][j2] = (f32x4){0.f, 0.f, 0.f, 0.f};

    u16x8 sa[4];
    if (AF) {
#pragma unroll
        for (int i = 0; i < 4; ++i)
            sa[i] = ld_f32_chunk((const float*)A + (size_t)(m0 + fr[i]) * K + fg[i] * 8);
    }

    for (int k0 = 0; k0 < K; k0 += 64) {
        if (k0 > 0) __syncthreads();
        if (AF) {
#pragma unroll
            for (int i = 0; i < 4; ++i)
                *(u16x8*)&As[ff[i] * 8] = sa[i];
        } else {
#pragma unroll
            for (int i = 0; i < 4; ++i)
                async_cp16((const unsigned short*)A + (size_t)(m0 + fr[i]) * K + k0 + fg[i] * 8,
                           &As[ff[i] * 8]);
        }
#pragma unroll
        for (int i = 0; i < 4; ++i)
            async_cp16((const unsigned short*)Bt + (size_t)(n0 + fr[i]) * K + k0 + fg[i] * 8,
                       &Bs[ff[i] * 8]);
        __syncthreads();

        if (AF && k0 + 64 < K) {
            const int kn = k0 + 64;
#pragma unroll
            for (int i = 0; i < 4; ++i)
                sa[i] = ld_f32_chunk((const float*)A + (size_t)(m0 + fr[i]) * K + kn + fg[i] * 8);
        }

#pragma unroll
        for (int ks = 0; ks < 2; ++ks) {
            bf16x8 af[4], bfr[4];
#pragma unroll
            for (int i = 0; i < 4; ++i) {
                const int row = wm * 64 + i * 16 + (lane & 15);
                const int col = wn * 64 + i * 16 + (lane & 15);
                const int g = ks * 4 + (lane >> 4);
                af[i]  = *(const bf16x8*)&As[row * 64 + (g ^ (row & 7)) * 8];
                bfr[i] = *(const bf16x8*)&Bs[col * 64 + (g ^ (col & 7)) * 8];
            }
#pragma unroll
            for (int i = 0; i < 4; ++i)
#pragma unroll
                for (int j2 = 0; j2 < 4; ++j2)
                    acc[i][j2] = __builtin_amdgcn_mfma_f32_16x16x32_bf16(
                        af[i], bfr[j2], acc[i][j2], 0, 0, 0);
        }
    }

    // Epilogue. C/D layout: col = lane&15, row = (lane>>4)*4 + reg.
#pragma unroll
    for (int i = 0; i < 4; ++i) {
        const int mrow0 = m0 + wm * 64 + i * 16 + (lane >> 4) * 4;
#pragma unroll
        for (int j2 = 0; j2 < 4; ++j2) {
            const int n = n0 + wn * 64 + j2 * 16 + (lane & 15);
            if (EPI == 5) {
                const int reg = n >> 10;  // tile-uniform: 0=Q, 1=K, 2=V
                const int nn = n & 1023;
                if (reg == 0) {
#pragma unroll
                    for (int r = 0; r < 4; ++r)
                        stf((bf16*)C + (size_t)(mrow0 + r) * 1024 + nn, acc[i][j2][r] * oscale);
                } else if (reg == 1) {
#pragma unroll
                    for (int r = 0; r < 4; ++r)
                        stf(C2 + (size_t)(mrow0 + r) * 1024 + nn, acc[i][j2][r]);
                } else {
                    const int bb = mrow0 >> 11, s = mrow0 & 2047;
                    ushort4 pk;
                    pk.x = f2bf_rne(acc[i][j2][0]);
                    pk.y = f2bf_rne(acc[i][j2][1]);
                    pk.z = f2bf_rne(acc[i][j2][2]);
                    pk.w = f2bf_rne(acc[i][j2][3]);
                    *(ushort4*)((unsigned short*)C3 + ((size_t)bb * 1024 + nn) * SS + s) = pk;
                }
            } else {
#pragma unroll
                for (int r = 0; r < 4; ++r) {
                    const size_t idx = (size_t)(mrow0 + r) * N + n;
                    float v = acc[i][j2][r];
                    if (EPI == 0) v *= oscale;
                    if (EPI == 2) { v += bias[n]; v = fmaxf(v, 0.0f); }
                    if (EPI == 6) v += bias[n] + cvt(resb[idx]);
                    if (EPI == 7) v += cvt(resb[idx]);
                    stf(&C[idx], v);
                }
            }
        }
    }
}

// ---------------------------------------------------------------------------
// Fused prep: one launch handles x->bf16 convert + ALL weight transposes.
// ---------------------------------------------------------------------------
__launch_bounds__(256)
__global__ void prep_kernel(const float* __restrict__ x,
                            const float* __restrict__ Wq, const float* __restrict__ Wk,
                            const float* __restrict__ Wv, const float* __restrict__ Wo,
                            const float* __restrict__ w_in, const float* __restrict__ w_out,
                            bf16* __restrict__ xb, bf16* __restrict__ WqkvT,
                            bf16* __restrict__ WoT, bf16* __restrict__ w_inT,
                            bf16* __restrict__ w_outT) {
    const int id = blockIdx.x;
    if (id < 8192) {
        const int i = id * 256 + threadIdx.x;
        const float4 v = ((const float4*)x)[i];
        ushort4 p;
        p.x = f2bf_rne(v.x); p.y = f2bf_rne(v.y); p.z = f2bf_rne(v.z); p.w = f2bf_rne(v.w);
        ((ushort4*)xb)[i] = p;
        return;
    }
    __shared__ float t[32][33];
    const int rem = id - 8192;
    const float* in;
    bf16* out;
    int R, C, bx, by;
    size_t in_o = 0, out_o = 0;
    if (rem < 3072) {
        const int z = rem >> 6, r2 = rem & 63;
        const int wi = z >> 4, head = z & 15;
        in = (wi == 0) ? Wq : (wi == 1) ? Wk : Wv;
        in_o = (size_t)head * DD * HD;
        out = WqkvT;
        out_o = (size_t)wi * DD * DD + (size_t)head * HD * DD;
        R = DD; C = HD;
        bx = (r2 & 1) * 32; by = (r2 >> 1) * 32;
    } else if (rem < 3072 + 1024) {
        const int r2 = rem - 3072;
        in = Wo; out = WoT; R = DD; C = DD;
        bx = (r2 & 31) * 32; by = (r2 >> 5) * 32;
    } else if (rem < 3072 + 1024 + 4096) {
        const int r2 = rem - 3072 - 1024;
        in = w_in; out = w_inT; R = DD; C = FF;
        bx = (r2 & 127) * 32; by = (r2 >> 7) * 32;
    } else {
        const int r2 = rem - 3072 - 1024 - 4096;
        in = w_out; out = w_outT; R = FF; C = DD;
        bx = (r2 & 31) * 32; by = (r2 >> 5) * 32;
    }
    const int tx = threadIdx.x & 31, ty = threadIdx.x >> 5;
#pragma unroll
    for (int i = 0; i < 32; i += 8)
        t[ty + i][tx] = in[in_o + (size_t)(by + ty + i) * C + bx + tx];
    __syncthreads();
#pragma unroll
    for (int i = 0; i < 32; i += 8)
        out[out_o + (size_t)(bx + ty + i) * R + by + tx] = __float2bfloat16(t[tx][ty + i]);
}

// ---------------------------------------------------------------------------
// MFMA causal flash attention, R15: pipelined staging.
// K double-buffered (Ks[2]), V single-buffered but issued a phase early.
// Iter kt: issue V(kt) + K(kt+1); vmcnt(4) retires K(kt) -> K latency hidden
// across a full tile; after QK^T+softmax, vmcnt(2) retires V(kt) -> V latency
// hidden behind QK^T. 3 raw barriers/tile; vmcnt(0) only on the last tile.
// LDS 33 KB keeps 4 blocks/CU (full K+V dbuf at 41 KB would drop to 3).
// Wait-count ledger (per-wave, issue order oldest-first):
//   kt=0:       [K0,V0,K1]=6 -> wait 4 kills K0; wait 2 kills V0.
//   0<kt<qi:    [Kt,Vt,Kt+1]=6 -> wait 4 kills Kt; wait 2 kills Vt.
//   kt=qi:      [Kq,Vq]=4    -> wait 2 kills Kq; wait 0 kills Vq.
// Buffer death: Vs readers (PV of kt) are barrier-separated from the V(kt+1)
// issue at top of kt+1; Ks[cur] readers (QK^T of kt) are barrier-separated
// from the K(kt+2) issue at top of kt+1. Ps is wave-local (lgkm-ordered).
// ---------------------------------------------------------------------------
__launch_bounds__(256, 4)
__global__ void attn_mfma(const bf16* __restrict__ Q, const bf16* __restrict__ K,
                          const bf16* __restrict__ VT, bf16* __restrict__ O) {
    __shared__ unsigned short Ks[2][64 * 64];
    __shared__ unsigned short Vs[64 * 64];
    __shared__ unsigned short Ps[64 * 72];

    const int tid = threadIdx.x;
    const int lane = tid & 63;
    const int w = tid >> 6;
    const int ln = lane & 15;
    const int qd = lane >> 4;
    const int bh = blockIdx.x;
    const int b = bh >> 4;
    const int h = bh & 15;
    const int qi = 31 - blockIdx.y;  // heavy blocks dispatch first
    const int q0 = qi * 64;

    bf16x8 aq[2];
    {
        const unsigned short* qp =
            (const unsigned short*)Q + ((size_t)b * SS + q0 + w * 16 + ln) * DD + h * HD;
        aq[0] = *(const bf16x8*)(qp + qd * 8);
        aq[1] = *(const bf16x8*)(qp + 32 + qd * 8);
    }

    int sf[2], sr[2], sg[2];
#pragma unroll
    for (int i = 0; i < 2; ++i) {
        sf[i] = tid + i * 256;
        sr[i] = sf[i] >> 3;
        sg[i] = (sf[i] & 7) ^ (sr[i] & 7);
    }
    const unsigned short* kbase = (const unsigned short*)K + (size_t)b * SS * DD + h * HD;
    const unsigned short* vbase = (const unsigned short*)VT + (size_t)(b * DD + h * HD) * SS;

    auto stageK = [&](int kt, int buf) {
        const int t0 = kt * 64;
#pragma unroll
        for (int i = 0; i < 2; ++i)
            async_cp16(kbase + (size_t)(t0 + sr[i]) * DD + sg[i] * 8, &Ks[buf][sf[i] * 8]);
    };
    auto stageV = [&](int kt) {
        const int t0 = kt * 64;
#pragma unroll
        for (int i = 0; i < 2; ++i)
            async_cp16(vbase + (size_t)sr[i] * SS + t0 + sg[i] * 8, &Vs[sf[i] * 8]);
    };

    f32x4 oacc[4];
#pragma unroll
    for (int e = 0; e < 4; ++e) oacc[e] = (f32x4){0.f, 0.f, 0.f, 0.f};
    float l_r[4] = {0.f, 0.f, 0.f, 0.f};

    stageK(0, 0);
    stageV(0);

    for (int kt = 0; kt <= qi; ++kt) {
        const int cur = kt & 1;
        if (kt > 0) stageV(kt);
        if (kt < qi) {
            stageK(kt + 1, cur ^ 1);
            s_wait_vmcnt<4>();  // retire K(kt); V(kt)+K(kt+1) stay in flight
        } else {
            s_wait_vmcnt<2>();  // retire K(qi); V(qi) stays in flight
        }
        sync_raw();  // publish K(kt)

        // ---- scores (exp2 domain) from Ks[cur] ----
        f32x4 sfr[4];
#pragma unroll
        for (int ct = 0; ct < 4; ++ct) {
            const int row = ct * 16 + ln;
            const bf16x8 b0 = *(const bf16x8*)&Ks[cur][row * 64 + ((qd) ^ (row & 7)) * 8];
            const bf16x8 b1 = *(const bf16x8*)&Ks[cur][row * 64 + ((4 + qd) ^ (row & 7)) * 8];
            f32x4 t = __builtin_amdgcn_mfma_f32_16x16x32_bf16(
                aq[0], b0, (f32x4){0.f, 0.f, 0.f, 0.f}, 0, 0, 0);
            sfr[ct] = __builtin_amdgcn_mfma_f32_16x16x32_bf16(aq[1], b1, t, 0, 0, 0);
        }

        // ---- causal mask (diagonal tile only): exp2(-1e30) = 0 ----
        if (kt == qi) {
#pragma unroll
            for (int ct = 0; ct < 4; ++ct) {
                const int tg = kt * 64 + ct * 16 + ln;
#pragma unroll
                for (int r = 0; r < 4; ++r) {
                    const int qg = q0 + w * 16 + qd * 4 + r;
                    if (tg > qg) sfr[ct][r] = -1e30f;
                }
            }
        }

        // ---- p = exp2(s); lane-local l accumulation ----
#pragma unroll
        for (int ct = 0; ct < 4; ++ct)
#pragma unroll
            for (int r = 0; r < 4; ++r)
                sfr[ct][r] = __builtin_amdgcn_exp2f(sfr[ct][r]);
#pragma unroll
        for (int r = 0; r < 4; ++r)
            l_r[r] += (sfr[0][r] + sfr[1][r]) + (sfr[2][r] + sfr[3][r]);

        // ---- P: C-layout -> LDS -> A-layout (wave-local slice) ----
#pragma unroll
        for (int ct = 0; ct < 4; ++ct)
#pragma unroll
            for (int r = 0; r < 4; ++r)
                Ps[(w * 16 + qd * 4 + r) * 72 + ct * 16 + ln] = f2bf_rne(sfr[ct][r]);
        const bf16x8 ap0 = *(const bf16x8*)&Ps[(w * 16 + ln) * 72 + qd * 8];
        const bf16x8 ap1 = *(const bf16x8*)&Ps[(w * 16 + ln) * 72 + 32 + qd * 8];

        // ---- V(kt) has been loading under QK^T; publish it now ----
        if (kt < qi) s_wait_vmcnt<2>();
        else         s_wait_vmcnt<0>();
        sync_raw();

        // ---- O += P @ V (no rescale) ----
#pragma unroll
        for (int et = 0; et < 4; ++et) {
            const int row = et * 16 + ln;
            const bf16x8 v0 = *(const bf16x8*)&Vs[row * 64 + ((qd) ^ (row & 7)) * 8];
            const bf16x8 v1 = *(const bf16x8*)&Vs[row * 64 + ((4 + qd) ^ (row & 7)) * 8];
            oacc[et] = __builtin_amdgcn_mfma_f32_16x16x32_bf16(ap0, v0, oacc[et], 0, 0, 0);
            oacc[et] = __builtin_amdgcn_mfma_f32_16x16x32_bf16(ap1, v1, oacc[et], 0, 0, 0);
        }

        // ---- end barrier: Vs dead block-wide, licenses next iter's stage ----
        asm volatile("s_waitcnt lgkmcnt(0)" ::: "memory");
        sync_raw();
    }

    // ---- ONE l reduction across the 16-lane col group, then finalize ----
#pragma unroll
    for (int st = 1; st <= 8; st <<= 1)
#pragma unroll
        for (int r = 0; r < 4; ++r)
            l_r[r] += __shfl_xor(l_r[r], st);
    float linv[4];
#pragma unroll
    for (int r = 0; r < 4; ++r) linv[r] = 1.0f / l_r[r];
    unsigned short* ob = (unsigned short*)O + (size_t)bh * SS * HD;
#pragma unroll
    for (int et = 0; et < 4; ++et)
#pragma unroll
        for (int r = 0; r < 4; ++r) {
            const int qg = q0 + w * 16 + qd * 4 + r;
            ob[(size_t)qg * HD + et * 16 + ln] = f2bf_rne(oacc[et][r] * linv[r]);
        }
}

// ---------------------------------------------------------------------------
// LayerNorm over D=1024, templated in/out dtype, fused shuffle reduction.
// ---------------------------------------------------------------------------
template <typename TIN, typename TOUT>
__launch_bounds__(256)
__global__ void ln_kernel(const TIN* __restrict__ X, TOUT* __restrict__ Y,
                          const float* __restrict__ g, const float* __restrict__ be) {
    const int row = blockIdx.x;
    const int tid = threadIdx.x;
    const int lane = tid & 63, w = tid >> 6;
    __shared__ float red[8];
    __shared__ float mv[2];

    float4 v;
    if (sizeof(TIN) == 4) {
        v = ((const float4*)((const float*)X + (size_t)row * DD))[tid];
    } else {
        const ushort4 u = ((const ushort4*)((const unsigned short*)X + (size_t)row * DD))[tid];
        v.x = __uint_as_float((unsigned)u.x << 16);
        v.y = __uint_as_float((unsigned)u.y << 16);
        v.z = __uint_as_float((unsigned)u.z << 16);
        v.w = __uint_as_float((unsigned)u.w << 16);
    }
    float s = (v.x + v.y) + (v.z + v.w);
    float q = (v.x * v.x + v.y * v.y) + (v.z * v.z + v.w * v.w);
#pragma unroll
    for (int st = 1; st < 64; st <<= 1) {
        s += __shfl_xor(s, st);
        q += __shfl_xor(q, st);
    }
    if (lane == 0) { red[w] = s; red[4 + w] = q; }
    __syncthreads();
    if (tid == 0) {
        const float ts = (red[0] + red[1]) + (red[2] + red[3]);
        const float tq = (red[4] + red[5]) + (red[6] + red[7]);
        const float mu = ts * (1.0f / DD);
        mv[0] = mu;
        mv[1] = rsqrtf(tq * (1.0f / DD) - mu * mu + LN_EPS);
    }
    __syncthreads();
    const float mu = mv[0], rs = mv[1];
    const float4 gg = ((const float4*)g)[tid];
    const float4 bb = ((const float4*)be)[tid];
    float o[4];
    o[0] = (v.x - mu) * rs * gg.x + bb.x;
    o[1] = (v.y - mu) * rs * gg.y + bb.y;
    o[2] = (v.z - mu) * rs * gg.z + bb.z;
    o[3] = (v.w - mu) * rs * gg.w + bb.w;
    if (sizeof(TOUT) == 4) {
        float4 of = {o[0], o[1], o[2], o[3]};
        ((float4*)((float*)Y + (size_t)row * DD))[tid] = of;
    } else {
        ushort4 p;
        p.x = f2bf_rne(o[0]); p.y = f2bf_rne(o[1]);
        p.z = f2bf_rne(o[2]); p.w = f2bf_rne(o[3]);
        ((ushort4*)((unsigned short*)Y + (size_t)row * DD))[tid] = p;
    }
}

extern "C" void kernel_launch(void* const* d_in, const int* in_sizes, int n_in,
                              void* d_out, int out_size, void* d_ws, size_t ws_size,
                              hipStream_t stream) {
    const float* x = (const float*)d_in[0];
    const float* Wq = (const float*)d_in[1];
    const float* Wk = (const float*)d_in[2];
    const float* Wv = (const float*)d_in[3];
    const float* Wo = (const float*)d_in[4];
    const float* g1 = (const float*)d_in[5];
    const float* be1 = (const float*)d_in[6];
    const float* w_in = (const float*)d_in[7];
    const float* b_in = (const float*)d_in[8];
    const float* w_out = (const float*)d_in[9];
    const float* b_out = (const float*)d_in[10];
    const float* g2 = (const float*)d_in[11];
    const float* be2 = (const float*)d_in[12];
    float* out = (float*)d_out;

    // Workspace (bytes), peak 120 MiB. DISJOINTNESS AUDIT (unchanged):
    //   Prep:     reads x,weights          -> writes xb[64,80), WqkvT[96,102),
    //                                         WoT[102,104), w_inT[104,112), w_outT[112,120)
    //   QKV:      reads xb,WqkvT           -> writes Qb[0,16) Kb[16,32) VT[32,48)
    //   attn:     reads Qb,Kb,VT           -> writes At[48,64)
    //   Wo-GEMM:  reads At,WoT,xb          -> writes X1b[80,96)   (EPI 7, bf16)
    //   LN1:      in-place X1b[80,96)
    //   FFN1:     reads X1b,w_inT          -> writes Hd[0,64)     (Qb/Kb/VT/At dead)
    //   FFN2:     reads Hd,X1b,w_outT      -> writes X2b[64,80)   (xb dead)
    //   LN2:      reads X2b                -> writes d_out
    char* wsb = (char*)d_ws;
    const size_t MiB = 1u << 20;
    bf16* Qb = (bf16*)(wsb);
    bf16* Kb = (bf16*)(wsb + 16 * MiB);
    bf16* VT = (bf16*)(wsb + 32 * MiB);
    bf16* At = (bf16*)(wsb + 48 * MiB);
    bf16* xb = (bf16*)(wsb + 64 * MiB);
    bf16* X1b = (bf16*)(wsb + 80 * MiB);
    bf16* Hd = (bf16*)(wsb);
    bf16* X2b = (bf16*)(wsb + 64 * MiB);
    bf16* WqkvT = (bf16*)(wsb + 96 * MiB);
    bf16* WoT = (bf16*)(wsb + 102 * MiB);
    bf16* w_inT = (bf16*)(wsb + 104 * MiB);
    bf16* w_outT = (bf16*)(wsb + 112 * MiB);
    (void)ws_size;

    const int M = BB * SS;  // 8192
    dim3 blk(256);

    // ---- Fused prep: x->bf16 + all weight transposes (one launch) ----
    prep_kernel<<<dim3(8192 + 3072 + 1024 + 4096 + 4096), blk, 0, stream>>>(
        x, Wq, Wk, Wv, Wo, w_in, w_out, xb, WqkvT, WoT, w_inT, w_outT);

    // ---- Fused QKV: xb @ [Wq|Wk|Wv] -> Qb(*QSCALE), Kb, VT ----
    // gx=24, BW=4 sub-bands (R4: net win ~7us vs BW=gx).
    mfma_gemm<bf16, bf16, 5, 4><<<dim3(3 * DD / 128, M / 128), blk, 0, stream>>>(
        xb, WqkvT, Qb, nullptr, nullptr, Kb, VT, M, 3 * DD, DD, QSCALE);

    // ---- MFMA causal flash attention (pipelined staging) ----
    attn_mfma<<<dim3(BB * HH, SS / 64), blk, 0, stream>>>(Qb, Kb, VT, At);

    // ---- attn(view) @ Wo + xb -> X1b bf16 (EPI 7); gx=8: BW=8 == R1 map ----
    mfma_gemm<bf16, bf16, 7, 8><<<dim3(DD / 128, M / 128), blk, 0, stream>>>(
        At, WoT, X1b, nullptr, xb, nullptr, nullptr, M, DD, DD, 1.0f);
    // LN1 in-place (bf16 -> bf16)
    ln_kernel<bf16, bf16><<<dim3(M), blk, 0, stream>>>(X1b, X1b, g1, be1);

    // ---- FFN1: relu(X1b @ w_in + b_in) -> Hd; BW=gx=32 (R1 map, R4 revert) ----
    mfma_gemm<bf16, bf16, 2, 32><<<dim3(FF / 128, M / 128), blk, 0, stream>>>(
        X1b, w_inT, Hd, b_in, nullptr, nullptr, nullptr, M, FF, DD, 1.0f);

    // ---- FFN2: Hd @ w_out + b_out + X1b -> X2b; gx=8: BW=8 == R1 map ----
    mfma_gemm<bf16, bf16, 6, 8><<<dim3(DD / 128, M / 128), blk, 0, stream>>>(
        Hd, w_outT, X2b, b_out, X1b, nullptr, nullptr, M, DD, FF, 1.0f);

    // ---- LN2: X2b bf16 -> fp32 out ----
    ln_kernel<bf16, float><<<dim3(M), blk, 0, stream>>>(X2b, out, g2, be2);
}